// Round 7
// baseline (257.945 us; speedup 1.0000x reference)
//
#include <hip/hip_runtime.h>
#include <math.h>

#define B_  32
#define S_  4096
#define E_  256
#define A_  256
#define DE_ 512

typedef __attribute__((ext_vector_type(8))) short short8;
typedef __attribute__((ext_vector_type(4))) float f32x4;

#define WAITV(n) asm volatile("s_waitcnt vmcnt(" #n ")" ::: "memory")
#define LGKM0()  asm volatile("s_waitcnt lgkmcnt(0)" ::: "memory")
#define BAR()    asm volatile("s_barrier" ::: "memory")

__device__ inline unsigned short f2bf(float x) {
    unsigned int u = __float_as_uint(x);
    u += 0x7FFFu + ((u >> 16) & 1u);      // round-to-nearest-even
    return (unsigned short)(u >> 16);
}
__device__ inline float tanh_fast(float x) {
    x = fminf(fmaxf(x, -15.f), 15.f);
    float t = __expf(2.f * x);
    return (t - 1.f) * __builtin_amdgcn_rcpf(t + 1.f);
}

// convert 8 floats to hi/lo bf16 planes and ds_write into single bf16 buffer
// (unit eu hi, 264+eu lo). lo plane TRUNCATED (residual error <= 2^-16 of x).
__device__ __forceinline__ void conv_write(float4 v0, float4 v1,
                                           unsigned short* buf, int eu,
                                           float& nacc)
{
    nacc += v0.x*v0.x + v0.y*v0.y + v0.z*v0.z + v0.w*v0.w
          + v1.x*v1.x + v1.y*v1.y + v1.z*v1.z + v1.w*v1.w;
    float xs[8] = {v0.x, v0.y, v0.z, v0.w, v1.x, v1.y, v1.z, v1.w};
    unsigned int hp[4], lp[4];
    #pragma unroll
    for (int j = 0; j < 4; ++j) {
        unsigned int u0 = __float_as_uint(xs[2*j])   & 0xFFFF0000u;
        unsigned int u1 = __float_as_uint(xs[2*j+1]) & 0xFFFF0000u;
        hp[j] = (u0 >> 16) | u1;
        lp[j] = (__float_as_uint(xs[2*j]   - __uint_as_float(u0)) >> 16)
              | ((__float_as_uint(xs[2*j+1] - __uint_as_float(u1)) >> 16) << 16);
    }
    *(uint4*)&buf[(size_t)eu * 8]         = make_uint4(hp[0], hp[1], hp[2], hp[3]);
    *(uint4*)&buf[(size_t)(264 + eu) * 8] = make_uint4(lp[0], lp[1], lp[2], lp[3]);
}

// ---- Prep: block 0..63 = pack We hi/lo bf16 (fragment order),
//            block 64..95 = proj, block 96 = zero attended region.
__global__ __launch_bounds__(256) void prep_kernel(
    const float* __restrict__ W, const float* __restrict__ dh,
    const float* __restrict__ bias, unsigned short* __restrict__ wepk,
    float* __restrict__ proj, float* __restrict__ out)
{
    __shared__ float dh_lds[E_];
    const int bk  = blockIdx.x;
    const int tid = threadIdx.x;
    if (bk < 64) {
        // unit = c*2048 + plane*1024 + kg*256 + a; 8 bf16 = We[a][c*32+kg*8..+8]
        const int idx = bk * 256 + tid;
        const int c     = idx >> 11;
        const int r     = idx & 2047;
        const int plane = r >> 10;
        const int kg    = (r >> 8) & 3;
        const int a     = r & 255;
        const float* src = W + (size_t)a * DE_ + E_ + c * 32 + kg * 8;
        unsigned int pk[4];
        #pragma unroll
        for (int j = 0; j < 4; ++j) {
            float x0 = src[2 * j], x1 = src[2 * j + 1];
            unsigned int u0 = __float_as_uint(x0) & 0xFFFF0000u;
            unsigned int u1 = __float_as_uint(x1) & 0xFFFF0000u;
            if (plane) {
                unsigned short l0 = f2bf(x0 - __uint_as_float(u0));
                unsigned short l1 = f2bf(x1 - __uint_as_float(u1));
                pk[j] = (unsigned int)l0 | ((unsigned int)l1 << 16);
            } else {
                pk[j] = (u0 >> 16) | u1;
            }
        }
        *(uint4*)&wepk[(size_t)idx * 8] = make_uint4(pk[0], pk[1], pk[2], pk[3]);
    } else if (bk < 96) {
        const int b = bk - 64;
        const int a = tid;
        dh_lds[a] = dh[b * E_ + a];
        __syncthreads();
        float acc = bias[a];
        const float* wrow = W + (size_t)a * DE_;
        #pragma unroll
        for (int d = 0; d < E_; d += 4) {
            float4 w = *(const float4*)(wrow + d);
            acc += dh_lds[d] * w.x + dh_lds[d+1] * w.y
                 + dh_lds[d+2] * w.z + dh_lds[d+3] * w.w;
        }
        proj[b * A_ + a] = acc;
    } else {
        #pragma unroll
        for (int j = tid; j < B_ * E_; j += 256) out[j] = 0.f;
    }
}

// ---- Scores v9: deep-MLP eo staging via global_load_lds 4-slot ring +
// counted vmcnt (T3/T4). Prologue bursts 4 chunks of DMA (8 instr/wave,
// ~96 KB/CU in flight) so the cold-L3 eo stream is BW-limited, not
// latency-limited. Per chunk: vmcnt(6..0)+s_barrier -> read own fp32 from
// LDS (linear, conflict-free) -> convert ONCE -> bf16 ds_write (66-stride,
// conflict-free) -> lgkmcnt(0)+s_barrier -> refill DMA slot -> 48 MFMA.
// No full vmcnt drain inside the loop. TS=64, wave=64s x 64a, 3 waves/SIMD.
__global__ __launch_bounds__(256, 3) void scores_kernel(
    const float* __restrict__ eo, const unsigned short* __restrict__ wepk,
    const float* __restrict__ proj,
    float* __restrict__ scores, float* __restrict__ nsq)
{
    // [0,32768): fp32 ring, 4 slots x 2048 floats
    // [32768,41216): bf16 hi/lo buffer, 528 units x 16 B
    // epilogue overlay (after full drain): red4 [64][66] @0; npart @16896; qpart @17920
    __shared__ __align__(16) unsigned char pool[41216];
    float*          fp32buf = (float*)pool;
    unsigned short* bfbuf   = (unsigned short*)(pool + 32768);

    const int tid = threadIdx.x;
    const int b   = blockIdx.x & (B_ - 1);
    const int s0  = (blockIdx.x >> 5) * 64;
    const int w   = tid >> 6, l = tid & 63;   // w = a-block of this wave
    const int lq  = l >> 4,  lr = l & 15;

    // staging map: wave w owns rows w*16..w*16+15; lane l -> row w*16+(l>>2),
    // kg quarter l&3 (8 floats). Same (row=tid>>2, quarter=tid&3) as before.
    const int ekg = l & 3;
    const int eu  = ekg * 66 + (w * 16 + (l >> 2));
    const float* gsrc = eo + (size_t)(s0 + w * 16 + (l >> 2)) * (B_ * E_)
                           + b * E_ + ekg * 8;

    // We fragment unit (16B units): c*2048 + plane*1024 + lq*256 + (w*64+nt*16+lr)
    const int wunit = lq * 256 + w * 64 + lr;

    f32x4 acc[4][4];
    #pragma unroll
    for (int i = 0; i < 4; ++i)
        #pragma unroll
        for (int j = 0; j < 4; ++j)
            acc[i][j] = (f32x4){0.f, 0.f, 0.f, 0.f};
    float nacc = 0.f;

    // proj for the epilogue (oldest vmem ops; iter-0 vmcnt(6) accounts for them)
    float pr[4];
    #pragma unroll
    for (int nt = 0; nt < 4; ++nt) pr[nt] = proj[b * A_ + w * 64 + nt * 16 + lr];

    // DMA: chunk cc -> slot cc&3 (two 16B-per-lane instructions)
    auto issue_dma = [&](int cc) {
        #pragma unroll
        for (int k = 0; k < 2; ++k) {
            __builtin_amdgcn_global_load_lds(
                (const __attribute__((address_space(1))) void*)(gsrc + cc * 32 + k * 4),
                (__attribute__((address_space(3))) void*)&fp32buf[(cc & 3) * 2048 + w * 512 + k * 256],
                16, 0, 0);
        }
    };

    // ---- prologue: burst-issue chunks 0..3 (deep MLP)
    issue_dma(0); issue_dma(1); issue_dma(2); issue_dma(3);

    #pragma unroll
    for (int c = 0; c < 8; ++c) {
        // wait for chunk c's DMA only (counted, never drain mid-loop)
        if      (c <= 4) WAITV(6);
        else if (c == 5) WAITV(4);
        else if (c == 6) WAITV(2);
        else             WAITV(0);
        BAR();   // all waves' chunk-c DMA retired -> LDS slot complete
        // ---- stage: read own fp32 (linear, 2-way-free), convert, bf16 write
        {
            float4 v0 = *(const float4*)&fp32buf[(c & 3) * 2048 + w * 512 + l * 4];
            float4 v1 = *(const float4*)&fp32buf[(c & 3) * 2048 + w * 512 + 256 + l * 4];
            conv_write(v0, v1, bfbuf, eu, nacc);
        }
        LGKM0();
        BAR();   // bf16 chunk c visible; all fp32 reads of slot c&3 retired
        if (c < 4) issue_dma(c + 4);   // refill the slot; flies under the MFMAs
        // ---- compute chunk c: We frags global->reg (L2-hot), 48 MFMA
        short8 bh[4], bl[4];
        {
            const unsigned short* wsrc = wepk + (size_t)(c * 2048 + wunit) * 8;
            #pragma unroll
            for (int nt = 0; nt < 4; ++nt) {
                bh[nt] = *(const short8*)(wsrc + (size_t)(nt * 16) * 8);
                bl[nt] = *(const short8*)(wsrc + (size_t)(1024 + nt * 16) * 8);
            }
        }
        short8 ah[2], al[2];
        #pragma unroll
        for (int mt = 0; mt < 2; ++mt) {
            const int au = lq * 66 + mt * 16 + lr;
            ah[mt] = *(const short8*)&bfbuf[(size_t)au * 8];
            al[mt] = *(const short8*)&bfbuf[(size_t)(264 + au) * 8];
        }
        #pragma unroll
        for (int mt = 0; mt < 2; ++mt) {
            #pragma unroll
            for (int nt = 0; nt < 4; ++nt) {
                acc[mt][nt] = __builtin_amdgcn_mfma_f32_16x16x32_bf16(ah[mt], bh[nt], acc[mt][nt], 0, 0, 0);
                acc[mt][nt] = __builtin_amdgcn_mfma_f32_16x16x32_bf16(ah[mt], bl[nt], acc[mt][nt], 0, 0, 0);
                acc[mt][nt] = __builtin_amdgcn_mfma_f32_16x16x32_bf16(al[mt], bh[nt], acc[mt][nt], 0, 0, 0);
            }
        }
        #pragma unroll
        for (int mt = 2; mt < 4; ++mt) {
            const int au = lq * 66 + mt * 16 + lr;
            short8 ah2 = *(const short8*)&bfbuf[(size_t)au * 8];
            short8 al2 = *(const short8*)&bfbuf[(size_t)(264 + au) * 8];
            #pragma unroll
            for (int nt = 0; nt < 4; ++nt) {
                acc[mt][nt] = __builtin_amdgcn_mfma_f32_16x16x32_bf16(ah2, bh[nt], acc[mt][nt], 0, 0, 0);
                acc[mt][nt] = __builtin_amdgcn_mfma_f32_16x16x32_bf16(ah2, bl[nt], acc[mt][nt], 0, 0, 0);
                acc[mt][nt] = __builtin_amdgcn_mfma_f32_16x16x32_bf16(al2, bh[nt], acc[mt][nt], 0, 0, 0);
            }
        }
    }
    __syncthreads();   // full drain before LDS overlay

    // ---- epilogue: tanh + reduce over a
    float* red4  = (float*)pool;                 // [64 a-groups][66] floats
    float* npart = (float*)(pool + 16896);       // 256 floats
    float* qpart = (float*)(pool + 17920);       // 256 floats
    #pragma unroll
    for (int mt = 0; mt < 4; ++mt) {
        #pragma unroll
        for (int r = 0; r < 4; ++r) {
            float s = 0.f;
            #pragma unroll
            for (int nt = 0; nt < 4; ++nt)
                s += tanh_fast(pr[nt] + acc[mt][nt][r]);
            // C/D layout: col = lr (a-dim), row = mt*16 + lq*4 + r (s-dim)
            red4[(w * 16 + lr) * 66 + (mt * 16 + lq * 4 + r)] = s;
        }
    }
    npart[tid] = nacc;    // partial (1/4 of E) of row tid>>2
    __syncthreads();
    {   // 256 threads: (row = tid>>2, quarter = tid&3) sums 16 of 64 a-groups
        const int row = tid >> 2, quarter = tid & 3;
        float s = 0.f;
        #pragma unroll
        for (int j = 0; j < 16; ++j) s += red4[(quarter * 16 + j) * 66 + row];
        qpart[quarter * 64 + row] = s;
    }
    __syncthreads();
    if (tid < 64) {
        scores[b * S_ + s0 + tid] = qpart[tid] + qpart[64 + tid]
                                  + qpart[128 + tid] + qpart[192 + tid];
        nsq[b * S_ + s0 + tid] = npart[4 * tid] + npart[4 * tid + 1]
                               + npart[4 * tid + 2] + npart[4 * tid + 3];
    }
}

// ---- Stats: per-b softmax stats computed ONCE (not per attend block).
// Writes attn_map, and overwrites nsq[] in-place with normalized probs
// (each element read-then-written only by its owner thread — race-free).
__global__ __launch_bounds__(256) void stats_kernel(
    const float* __restrict__ scores, float* __restrict__ nsq_pv,
    float* __restrict__ out)
{
    __shared__ float red[256];
    const int tid  = threadIdx.x;
    const int b    = blockIdx.x & (B_ - 1);
    const int part = blockIdx.x >> 5;      // 0..7: which 512-slice this block writes
    float v[16];
    float m = -1e30f;
    #pragma unroll
    for (int i = 0; i < 16; ++i) {
        v[i] = scores[b * S_ + i * 256 + tid];
        m = fmaxf(m, v[i]);
    }
    red[tid] = m;
    __syncthreads();
    for (int off = 128; off > 0; off >>= 1) {
        if (tid < off) red[tid] = fmaxf(red[tid], red[tid + off]);
        __syncthreads();
    }
    m = red[0];
    __syncthreads();
    float sum = 0.f;
    #pragma unroll
    for (int i = 0; i < 16; ++i) sum += __expf(v[i] - m);
    red[tid] = sum;
    __syncthreads();
    for (int off = 128; off > 0; off >>= 1) {
        if (tid < off) red[tid] += red[tid + off];
        __syncthreads();
    }
    const float inv = 1.f / red[0];
    #pragma unroll
    for (int j = 0; j < 2; ++j) {
        const int i = part * 2 + j;
        const int s = i * 256 + tid;
        const float pv = __expf(v[i] - m) * inv;
        out[B_ * E_ + b * S_ + s] = pv * sqrtf(nsq_pv[b * S_ + s]);
        nsq_pv[b * S_ + s] = pv;
    }
}

// ---- Attend: pure-bandwidth accumulation (no softmax recompute).
__global__ __launch_bounds__(256) void attend_kernel(
    const float* __restrict__ eo, const float* __restrict__ pv,
    float* __restrict__ out)
{
    __shared__ float4 acc_red[4][64];
    const int tid = threadIdx.x;
    const int b   = blockIdx.x & (B_ - 1);
    const int ch  = blockIdx.x / B_;
    const int le = tid & 63, sg = tid >> 6;
    const int s0 = ch * 128 + sg * 32;
    float4 a = make_float4(0.f, 0.f, 0.f, 0.f);
    #pragma unroll 8
    for (int s = 0; s < 32; ++s) {
        float p = pv[b * S_ + s0 + s];
        float4 e = *(const float4*)(eo + (size_t)(s0 + s) * (B_ * E_)
                                       + b * E_ + le * 4);
        a.x = fmaf(p, e.x, a.x);
        a.y = fmaf(p, e.y, a.y);
        a.z = fmaf(p, e.z, a.z);
        a.w = fmaf(p, e.w, a.w);
    }
    acc_red[sg][le] = a;
    __syncthreads();
    if (tid < 64) {
        float4 a0 = acc_red[0][tid], a1 = acc_red[1][tid];
        float4 a2 = acc_red[2][tid], a3 = acc_red[3][tid];
        float* dst = out + b * E_ + tid * 4;
        atomicAdd(dst + 0, a0.x + a1.x + a2.x + a3.x);
        atomicAdd(dst + 1, a0.y + a1.y + a2.y + a3.y);
        atomicAdd(dst + 2, a0.z + a1.z + a2.z + a3.z);
        atomicAdd(dst + 3, a0.w + a1.w + a2.w + a3.w);
    }
}

extern "C" void kernel_launch(void* const* d_in, const int* in_sizes, int n_in,
                              void* d_out, int out_size, void* d_ws, size_t ws_size,
                              hipStream_t stream)
{
    const float* dh   = (const float*)d_in[0];  // (1,B,D)
    const float* eo   = (const float*)d_in[1];  // (S,B,E)
    const float* W    = (const float*)d_in[2];  // (A, D+E)
    const float* bias = (const float*)d_in[3];  // (A,)
    float* out = (float*)d_out;                 // [attended 8192 | attn_map 131072]
    float* ws  = (float*)d_ws;

    float* projb  = ws;                           // 8192 floats
    float* nsqb   = ws + 8192;                    // 131072 floats (nsq, then pv in-place)
    float* scores = nsqb + S_ * B_;               // 131072 floats
    unsigned short* wepk = (unsigned short*)(scores + S_ * B_);  // 256 KB packed We

    prep_kernel   <<<97,              256, 0, stream>>>(W, dh, bias, wepk, projb, out);
    scores_kernel <<<B_ * (S_ / 64),  256, 0, stream>>>(eo, wepk, projb, scores, nsqb);
    stats_kernel  <<<B_ * 8,          256, 0, stream>>>(scores, nsqb, out);
    attend_kernel <<<B_ * (S_ / 128), 256, 0, stream>>>(eo, nsqb, out);
}

// Round 8
// 241.694 us; speedup vs baseline: 1.0672x; 1.0672x over previous
//
#include <hip/hip_runtime.h>
#include <math.h>

#define B_  32
#define S_  4096
#define E_  256
#define A_  256
#define DE_ 512

typedef __attribute__((ext_vector_type(8))) short short8;
typedef __attribute__((ext_vector_type(4))) float f32x4;

__device__ inline unsigned short f2bf(float x) {
    unsigned int u = __float_as_uint(x);
    u += 0x7FFFu + ((u >> 16) & 1u);      // round-to-nearest-even
    return (unsigned short)(u >> 16);
}
__device__ inline float tanh_fast(float x) {
    x = fminf(fmaxf(x, -15.f), 15.f);
    float t = __expf(2.f * x);
    return (t - 1.f) * __builtin_amdgcn_rcpf(t + 1.f);
}

// convert 8 floats to hi/lo bf16 planes, ds_write into dbuf (unit eu hi,
// 264+eu lo) AND an RNE-rounded bf16 copy into the retain region rt
// (consumed by the fused-attend P epilogue). Accumulates sum of squares.
__device__ __forceinline__ void conv_write(float4 v0, float4 v1,
                                           unsigned short* buf, int eu,
                                           unsigned short* rt,
                                           float& nacc)
{
    nacc += v0.x*v0.x + v0.y*v0.y + v0.z*v0.z + v0.w*v0.w
          + v1.x*v1.x + v1.y*v1.y + v1.z*v1.z + v1.w*v1.w;
    float xs[8] = {v0.x, v0.y, v0.z, v0.w, v1.x, v1.y, v1.z, v1.w};
    unsigned int hp[4], lp[4], rp[4];
    #pragma unroll
    for (int j = 0; j < 4; ++j) {
        unsigned int u0 = __float_as_uint(xs[2*j])   & 0xFFFF0000u;
        unsigned int u1 = __float_as_uint(xs[2*j+1]) & 0xFFFF0000u;
        hp[j] = (u0 >> 16) | u1;
        lp[j] = (unsigned int)f2bf(xs[2*j]   - __uint_as_float(u0))
              | ((unsigned int)f2bf(xs[2*j+1] - __uint_as_float(u1)) << 16);
        rp[j] = (unsigned int)f2bf(xs[2*j])
              | ((unsigned int)f2bf(xs[2*j+1]) << 16);
    }
    *(uint4*)&buf[(size_t)eu * 8]         = make_uint4(hp[0], hp[1], hp[2], hp[3]);
    *(uint4*)&buf[(size_t)(264 + eu) * 8] = make_uint4(lp[0], lp[1], lp[2], lp[3]);
    *(uint4*)&rt[(size_t)eu * 8]          = make_uint4(rp[0], rp[1], rp[2], rp[3]);
}

// ---- Prep: block 0..63 = pack We hi/lo bf16 (fragment order),
//            block 64..95 = proj.
__global__ __launch_bounds__(256) void prep_kernel(
    const float* __restrict__ W, const float* __restrict__ dh,
    const float* __restrict__ bias, unsigned short* __restrict__ wepk,
    float* __restrict__ proj)
{
    __shared__ float dh_lds[E_];
    const int bk  = blockIdx.x;
    const int tid = threadIdx.x;
    if (bk < 64) {
        // unit = c*2048 + plane*1024 + kg*256 + a; 8 bf16 = We[a][c*32+kg*8..+8]
        const int idx = bk * 256 + tid;
        const int c     = idx >> 11;
        const int r     = idx & 2047;
        const int plane = r >> 10;
        const int kg    = (r >> 8) & 3;
        const int a     = r & 255;
        const float* src = W + (size_t)a * DE_ + E_ + c * 32 + kg * 8;
        unsigned int pk[4];
        #pragma unroll
        for (int j = 0; j < 4; ++j) {
            float x0 = src[2 * j], x1 = src[2 * j + 1];
            unsigned int u0 = __float_as_uint(x0) & 0xFFFF0000u;
            unsigned int u1 = __float_as_uint(x1) & 0xFFFF0000u;
            if (plane) {
                unsigned short l0 = f2bf(x0 - __uint_as_float(u0));
                unsigned short l1 = f2bf(x1 - __uint_as_float(u1));
                pk[j] = (unsigned int)l0 | ((unsigned int)l1 << 16);
            } else {
                pk[j] = (u0 >> 16) | u1;
            }
        }
        *(uint4*)&wepk[(size_t)idx * 8] = make_uint4(pk[0], pk[1], pk[2], pk[3]);
    } else {
        const int b = bk - 64;
        const int a = tid;
        dh_lds[a] = dh[b * E_ + a];
        __syncthreads();
        float acc = bias[a];
        const float* wrow = W + (size_t)a * DE_;
        #pragma unroll
        for (int d = 0; d < E_; d += 4) {
            float4 w = *(const float4*)(wrow + d);
            acc += dh_lds[d] * w.x + dh_lds[d+1] * w.y
                 + dh_lds[d+2] * w.z + dh_lds[d+3] * w.w;
        }
        proj[b * A_ + a] = acc;
    }
}

// ---- Scores v10 (fused attend): v7's 1-barrier double-buffered K-loop,
// plus a retained RNE-bf16 copy of all 8 eo chunks (33.8 KB LDS).
// Epilogue additionally computes flash-style per-block softmax partials:
// m_blk, Z_blk, P[e] = sum_s exp(sc_s - m_blk) * eo_hi[s][e] -> Pbuf.
// The 134 MB attend re-read of eo is thereby eliminated.
// LDS 52736 B -> still 3 blocks/CU. TS=64, wave=64s x 64a, 3 waves/SIMD.
__global__ __launch_bounds__(256, 3) void scores_kernel(
    const float* __restrict__ eo, const unsigned short* __restrict__ wepk,
    const float* __restrict__ proj,
    float* __restrict__ scores, float* __restrict__ nsq,
    float* __restrict__ Pbuf)
{
    // [0,16896): two eo dbuf buffers of 528 units (16 B each)
    // [18944,52736): retain region, 8 chunks x 264 units (RNE hi bf16)
    // epilogue overlay on [0,18944): red4 [64][66] @0; npart @16896; qpart @17920
    __shared__ __align__(16) unsigned char pool[52736];
    unsigned short* eo_hl  = (unsigned short*)pool;
    unsigned short* retain = (unsigned short*)(pool + 18944);

    const int tid = threadIdx.x;
    const int b   = blockIdx.x & (B_ - 1);
    const int s0  = (blockIdx.x >> 5) * 64;
    const int w   = tid >> 6, l = tid & 63;   // w = a-block of this wave
    const int lq  = l >> 4,  lr = l & 15;

    // eo staging map: 4 lanes per row, lane covers one kg (8 floats, 32 B)
    const int erow = tid >> 2;          // 0..63
    const int ekg  = tid & 3;
    const float* ebase = eo + (size_t)(s0 + erow) * (B_ * E_) + b * E_ + ekg * 8;
    const int eu = ekg * 66 + erow;     // write unit within a buffer

    // We fragment unit (16B units): c*2048 + plane*1024 + lq*256 + (w*64+nt*16+lr)
    const int wunit = lq * 256 + w * 64 + lr;

    f32x4 acc[4][4];
    #pragma unroll
    for (int i = 0; i < 4; ++i)
        #pragma unroll
        for (int j = 0; j < 4; ++j)
            acc[i][j] = (f32x4){0.f, 0.f, 0.f, 0.f};
    float nacc = 0.f;

    // proj values for the epilogue (tiny, L2-hot)
    float pr[4];
    #pragma unroll
    for (int nt = 0; nt < 4; ++nt) pr[nt] = proj[b * A_ + w * 64 + nt * 16 + lr];

    // ---- prologue: stage chunk 0 into buf0 (+retain), load chunk-1 regs
    {
        float4 v0 = *(const float4*)(ebase);
        float4 v1 = *(const float4*)(ebase + 4);
        conv_write(v0, v1, eo_hl, eu, retain, nacc);
    }
    float4 va0 = *(const float4*)(ebase + 32);
    float4 va1 = *(const float4*)(ebase + 36);
    __syncthreads();

    for (int c = 0; c < 8; ++c) {
        const int p = c & 1;
        unsigned short* rb = eo_hl + (size_t)p * 528 * 8;        // read buf
        unsigned short* wb = eo_hl + (size_t)(1 - p) * 528 * 8;  // write buf

        // ---- We fragment loads (global, L2-hot; in flight through convert)
        short8 bh[4], bl[4];
        {
            const unsigned short* wsrc = wepk + (size_t)(c * 2048 + wunit) * 8;
            #pragma unroll
            for (int nt = 0; nt < 4; ++nt) {
                bh[nt] = *(const short8*)(wsrc + (size_t)(nt * 16) * 8);
                bl[nt] = *(const short8*)(wsrc + (size_t)(1024 + nt * 16) * 8);
            }
        }
        // ---- A-frag reads, first half (mt 0,1)
        short8 ah[2], al[2];
        #pragma unroll
        for (int mt = 0; mt < 2; ++mt) {
            const int au = lq * 66 + mt * 16 + lr;
            ah[mt] = *(const short8*)&rb[(size_t)au * 8];
            al[mt] = *(const short8*)&rb[(size_t)(264 + au) * 8];
        }
        // ---- convert + write chunk c+1 (dbuf + retain); hides ds_read latency
        if (c < 7) conv_write(va0, va1, wb, eu,
                              retain + (size_t)(c + 1) * 264 * 8, nacc);
        // ---- prefetch eo chunk c+2
        if (c < 6) {
            va0 = *(const float4*)(ebase + (c + 2) * 32);
            va1 = *(const float4*)(ebase + (c + 2) * 32 + 4);
        }
        // ---- MFMA first half
        #pragma unroll
        for (int mt = 0; mt < 2; ++mt) {
            #pragma unroll
            for (int nt = 0; nt < 4; ++nt) {
                acc[mt][nt] = __builtin_amdgcn_mfma_f32_16x16x32_bf16(ah[mt], bh[nt], acc[mt][nt], 0, 0, 0);
                acc[mt][nt] = __builtin_amdgcn_mfma_f32_16x16x32_bf16(ah[mt], bl[nt], acc[mt][nt], 0, 0, 0);
                acc[mt][nt] = __builtin_amdgcn_mfma_f32_16x16x32_bf16(al[mt], bh[nt], acc[mt][nt], 0, 0, 0);
            }
        }
        // ---- A-frag reads + MFMA, second half (mt 2,3)
        #pragma unroll
        for (int mt = 2; mt < 4; ++mt) {
            const int au = lq * 66 + mt * 16 + lr;
            short8 ah2 = *(const short8*)&rb[(size_t)au * 8];
            short8 al2 = *(const short8*)&rb[(size_t)(264 + au) * 8];
            #pragma unroll
            for (int nt = 0; nt < 4; ++nt) {
                acc[mt][nt] = __builtin_amdgcn_mfma_f32_16x16x32_bf16(ah2, bh[nt], acc[mt][nt], 0, 0, 0);
                acc[mt][nt] = __builtin_amdgcn_mfma_f32_16x16x32_bf16(ah2, bl[nt], acc[mt][nt], 0, 0, 0);
                acc[mt][nt] = __builtin_amdgcn_mfma_f32_16x16x32_bf16(al2, bh[nt], acc[mt][nt], 0, 0, 0);
            }
        }
        if (c < 7) __syncthreads();
    }
    __syncthreads();   // all fragment reads done before LDS overlay

    // ---- epilogue: tanh + reduce over a
    float* red4  = (float*)pool;                 // [64 a-groups][66] floats
    float* npart = (float*)(pool + 16896);       // 256 floats (later reused as ws[64])
    float* qpart = (float*)(pool + 17920);       // 256 floats
    #pragma unroll
    for (int mt = 0; mt < 4; ++mt) {
        #pragma unroll
        for (int r = 0; r < 4; ++r) {
            float s = 0.f;
            #pragma unroll
            for (int nt = 0; nt < 4; ++nt)
                s += tanh_fast(pr[nt] + acc[mt][nt][r]);
            // C/D layout: col = lr (a-dim), row = mt*16 + lq*4 + r (s-dim)
            red4[(w * 16 + lr) * 66 + (mt * 16 + lq * 4 + r)] = s;
        }
    }
    npart[tid] = nacc;    // partial (1/4 of E) of row tid>>2
    __syncthreads();
    {   // 256 threads: (row = tid>>2, quarter = tid&3) sums 16 of 64 a-groups
        const int row = tid >> 2, quarter = tid & 3;
        float s = 0.f;
        #pragma unroll
        for (int j = 0; j < 16; ++j) s += red4[(quarter * 16 + j) * 66 + row];
        qpart[quarter * 64 + row] = s;
    }
    __syncthreads();
    float* ws = npart;   // npart dead after the nsq line below; wave 0 only
    if (tid < 64) {
        const float sc = qpart[tid] + qpart[64 + tid]
                       + qpart[128 + tid] + qpart[192 + tid];
        scores[b * S_ + s0 + tid] = sc;
        nsq[b * S_ + s0 + tid] = npart[4 * tid] + npart[4 * tid + 1]
                               + npart[4 * tid + 2] + npart[4 * tid + 3];
        // wave-0 softmax partial stats over this block's 64 rows
        float mb = sc;
        #pragma unroll
        for (int off = 32; off > 0; off >>= 1)
            mb = fmaxf(mb, __shfl_xor(mb, off, 64));
        const float wv = __expf(sc - mb);
        float zb = wv;
        #pragma unroll
        for (int off = 32; off > 0; off >>= 1)
            zb += __shfl_xor(zb, off, 64);
        ws[tid] = wv;
        if (tid == 0) {
            Pbuf[(size_t)blockIdx.x * 258 + 256] = mb;
            Pbuf[(size_t)blockIdx.x * 258 + 257] = zb;
        }
    }
    __syncthreads();
    // ---- fused-attend partial: P[e] = sum_s ws[s] * eo_rne[s][e]
    {
        const int c2 = tid >> 5, kg2 = (tid >> 3) & 3, j2 = tid & 7;
        const unsigned short* rt = retain + (size_t)(c2 * 264 + kg2 * 66) * 8 + j2;
        float accp = 0.f;
        #pragma unroll 8
        for (int s = 0; s < 64; ++s)
            accp += ws[s] * __uint_as_float((unsigned int)rt[(size_t)s * 8] << 16);
        Pbuf[(size_t)blockIdx.x * 258 + tid] = accp;
    }
}

// ---- Stats: per-b softmax computed once per slice-block; writes attn_map.
__global__ __launch_bounds__(256) void stats_kernel(
    const float* __restrict__ scores, const float* __restrict__ nsq,
    float* __restrict__ out)
{
    __shared__ float red[256];
    const int tid  = threadIdx.x;
    const int b    = blockIdx.x & (B_ - 1);
    const int part = blockIdx.x >> 5;      // 0..7: which 512-slice this block writes
    float v[16];
    float m = -1e30f;
    #pragma unroll
    for (int i = 0; i < 16; ++i) {
        v[i] = scores[b * S_ + i * 256 + tid];
        m = fmaxf(m, v[i]);
    }
    red[tid] = m;
    __syncthreads();
    for (int off = 128; off > 0; off >>= 1) {
        if (tid < off) red[tid] = fmaxf(red[tid], red[tid + off]);
        __syncthreads();
    }
    m = red[0];
    __syncthreads();
    float sum = 0.f;
    #pragma unroll
    for (int i = 0; i < 16; ++i) sum += __expf(v[i] - m);
    red[tid] = sum;
    __syncthreads();
    for (int off = 128; off > 0; off >>= 1) {
        if (tid < off) red[tid] += red[tid + off];
        __syncthreads();
    }
    const float inv = 1.f / red[0];
    #pragma unroll
    for (int j = 0; j < 2; ++j) {
        const int i = part * 2 + j;
        const int s = i * 256 + tid;
        const float pv = __expf(v[i] - m) * inv;
        out[B_ * E_ + b * S_ + s] = pv * sqrtf(nsq[b * S_ + s]);
    }
}

// ---- Combine: attended[b][e] from 64 per-block partials (2 MB total read,
// replaces attend's 134 MB eo re-read).
__global__ __launch_bounds__(256) void combine_kernel(
    const float* __restrict__ Pbuf, float* __restrict__ out)
{
    __shared__ float mz[128];
    __shared__ float sc[64];
    const int tid = threadIdx.x;
    const int b   = blockIdx.x;
    if (tid < 64)       mz[tid] = Pbuf[(size_t)(tid * 32 + b) * 258 + 256];
    else if (tid < 128) mz[tid] = Pbuf[(size_t)((tid - 64) * 32 + b) * 258 + 257];
    __syncthreads();
    float m = -1e30f;
    #pragma unroll
    for (int i = 0; i < 64; ++i) m = fmaxf(m, mz[i]);
    float Z = 0.f;
    #pragma unroll
    for (int i = 0; i < 64; ++i) Z += mz[64 + i] * __expf(mz[i] - m);
    if (tid < 64) sc[tid] = __expf(mz[tid] - m);
    __syncthreads();
    float acc = 0.f;
    #pragma unroll 8
    for (int blk = 0; blk < 64; ++blk)
        acc += Pbuf[(size_t)(blk * 32 + b) * 258 + tid] * sc[blk];
    out[b * E_ + tid] = acc / Z;
}

extern "C" void kernel_launch(void* const* d_in, const int* in_sizes, int n_in,
                              void* d_out, int out_size, void* d_ws, size_t ws_size,
                              hipStream_t stream)
{
    const float* dh   = (const float*)d_in[0];  // (1,B,D)
    const float* eo   = (const float*)d_in[1];  // (S,B,E)
    const float* W    = (const float*)d_in[2];  // (A, D+E)
    const float* bias = (const float*)d_in[3];  // (A,)
    float* out = (float*)d_out;                 // [attended 8192 | attn_map 131072]
    float* ws  = (float*)d_ws;

    float* projb  = ws;                           // 8192 floats
    float* nsqb   = ws + 8192;                    // 131072 floats
    float* scores = nsqb + S_ * B_;               // 131072 floats
    float* Pbuf   = scores + S_ * B_;             // 2048*258 floats (P + m,Z per block)
    unsigned short* wepk = (unsigned short*)(Pbuf + 2048 * 258);  // 256 KB packed We

    prep_kernel    <<<96,              256, 0, stream>>>(W, dh, bias, wepk, projb);
    scores_kernel  <<<B_ * (S_ / 64),  256, 0, stream>>>(eo, wepk, projb, scores, nsqb, Pbuf);
    stats_kernel   <<<B_ * 8,          256, 0, stream>>>(scores, nsqb, out);
    combine_kernel <<<B_,              256, 0, stream>>>(Pbuf, out);
}